// Round 4
// baseline (507.398 us; speedup 1.0000x reference)
//
#include <hip/hip_runtime.h>

// Sparsemax along last dim of (8192 x 8192) fp32.
// tau in [max-1, max): support subset of {x > max-1} (~21/row, Gaussian).
// R4: one WAVE per row, zero barriers, zero LDS. Pass 1: wave max.
// Pass 2: write zeros for non-candidates, capture candidates (val,idx) in a
// 7-deep per-lane register queue. Michelot on registers via shuffles, then
// scatter the few candidate outputs. Overflow -> rescan fallback (benign
// identical-value double writes only).

#define D 8192
#define BLOCK 256
#define NF4 (D / 4 / 64)  // 32 float4 per lane per row
#define CAPL 7            // per-lane candidate capacity
#define NEG_HUGE -3.402823466e+38f

typedef float v4f __attribute__((ext_vector_type(4)));

__global__ __launch_bounds__(BLOCK, 8) void sparsemax_kernel(
    const float* __restrict__ x, float* __restrict__ out) {
  const int lane = threadIdx.x & 63;
  const int wave = threadIdx.x >> 6;
  const long long row = (long long)blockIdx.x * 4 + wave;
  const float4* __restrict__ xr = (const float4*)(x + row * (long long)D);
  float* __restrict__ orow = out + row * (long long)D;
  float4* __restrict__ or4 = (float4*)orow;

  // ---- pass 1: exact row max ----
  float m = NEG_HUGE;
#pragma unroll 4
  for (int j = 0; j < NF4; ++j) {
    float4 f = xr[lane + 64 * j];
    m = fmaxf(m, fmaxf(fmaxf(f.x, f.y), fmaxf(f.z, f.w)));
  }
#pragma unroll
  for (int o = 1; o < 64; o <<= 1) m = fmaxf(m, __shfl_xor(m, o, 64));
  const float L = m - 1.0f;  // tau >= L always

  // ---- pass 2: zeros for non-candidates, capture candidates in regs ----
  float tv[CAPL];
  int ta[CAPL];
  int cnt = 0;
#pragma unroll
  for (int k = 0; k < CAPL; ++k) { tv[k] = NEG_HUGE; ta[k] = 0; }

#define PUSH(val, idx)                                              \
  do {                                                              \
    tv[6] = tv[5]; ta[6] = ta[5]; tv[5] = tv[4]; ta[5] = ta[4];     \
    tv[4] = tv[3]; ta[4] = ta[3]; tv[3] = tv[2]; ta[3] = ta[2];     \
    tv[2] = tv[1]; ta[2] = ta[1]; tv[1] = tv[0]; ta[1] = ta[0];     \
    tv[0] = (val); ta[0] = (idx); ++cnt;                            \
  } while (0)

#pragma unroll 4
  for (int j = 0; j < NF4; ++j) {
    const int fi = lane + 64 * j;
    float4 f = xr[fi];
    const bool q0 = f.x > L, q1 = f.y > L, q2 = f.z > L, q3 = f.w > L;
    if (!(q0 | q1 | q2 | q3)) {
      v4f z = {0.f, 0.f, 0.f, 0.f};
      __builtin_nontemporal_store(z, (v4f*)&or4[fi]);
    } else {  // rare (~1% of float4s): per-component handling
      const int e0 = 4 * fi;
      if (q0) PUSH(f.x, e0 + 0); else __builtin_nontemporal_store(0.f, &orow[e0 + 0]);
      if (q1) PUSH(f.y, e0 + 1); else __builtin_nontemporal_store(0.f, &orow[e0 + 1]);
      if (q2) PUSH(f.z, e0 + 2); else __builtin_nontemporal_store(0.f, &orow[e0 + 2]);
      if (q3) PUSH(f.w, e0 + 3); else __builtin_nontemporal_store(0.f, &orow[e0 + 3]);
    }
  }

  const unsigned long long ovf = __ballot(cnt > CAPL);

  if (ovf == 0ULL) {
    // ---- Michelot on register-resident candidates (shuffles only) ----
    float s = 0.f, c = (float)cnt;
#pragma unroll
    for (int k = 0; k < CAPL; ++k) s += (k < cnt) ? tv[k] : 0.f;
#pragma unroll
    for (int o = 1; o < 64; o <<= 1) {
      s += __shfl_xor(s, o, 64);
      c += __shfl_xor(c, o, 64);
    }
    float tau = (s - 1.0f) / c;  // c >= 1: max is always a candidate
    float prev = c;
    for (int it = 0; it < 512; ++it) {
      float s2 = 0.f, c2 = 0.f;
#pragma unroll
      for (int k = 0; k < CAPL; ++k)
        if (tv[k] > tau) { s2 += tv[k]; c2 += 1.f; }
#pragma unroll
      for (int o = 1; o < 64; o <<= 1) {
        s2 += __shfl_xor(s2, o, 64);
        c2 += __shfl_xor(c2, o, 64);
      }
      if (c2 == prev) break;  // support stable => tau exact
      tau = (s2 - 1.0f) / c2;
      prev = c2;
    }
    // scatter the candidate outputs (each cell written exactly once)
#pragma unroll
    for (int k = 0; k < CAPL; ++k)
      if (k < cnt) orow[ta[k]] = fmaxf(tv[k] - tau, 0.f);
  } else {
    // ---- rare fallback: rescan-based Michelot, then rewrite full row.
    // Non-candidate cells get rewritten with the same 0 -> benign.
    float tau = L, prev = -1.f;
    for (int it = 0; it < 256; ++it) {
      float s = 0.f, c = 0.f;
#pragma unroll 4
      for (int j = 0; j < NF4; ++j) {
        float4 f = xr[lane + 64 * j];
        if (f.x > tau) { s += f.x; c += 1.f; }
        if (f.y > tau) { s += f.y; c += 1.f; }
        if (f.z > tau) { s += f.z; c += 1.f; }
        if (f.w > tau) { s += f.w; c += 1.f; }
      }
#pragma unroll
      for (int o = 1; o < 64; o <<= 1) {
        s += __shfl_xor(s, o, 64);
        c += __shfl_xor(c, o, 64);
      }
      if (c == prev) break;
      tau = (s - 1.0f) / c;
      prev = c;
    }
#pragma unroll 4
    for (int j = 0; j < NF4; ++j) {
      const int fi = lane + 64 * j;
      float4 f = xr[fi];
      v4f o;
      o.x = fmaxf(f.x - tau, 0.f);
      o.y = fmaxf(f.y - tau, 0.f);
      o.z = fmaxf(f.z - tau, 0.f);
      o.w = fmaxf(f.w - tau, 0.f);
      __builtin_nontemporal_store(o, (v4f*)&or4[fi]);
    }
  }
}

extern "C" void kernel_launch(void* const* d_in, const int* in_sizes, int n_in,
                              void* d_out, int out_size, void* d_ws, size_t ws_size,
                              hipStream_t stream) {
  const float* x = (const float*)d_in[0];
  float* out = (float*)d_out;
  const int rows = in_sizes[0] / D;  // 8192
  sparsemax_kernel<<<rows / 4, BLOCK, 0, stream>>>(x, out);
}

// Round 5
// 506.362 us; speedup vs baseline: 1.0020x; 1.0020x over previous
//
#include <hip/hip_runtime.h>

// Sparsemax along last dim of (8192 x 8192) fp32 — two-kernel split.
//
// K1 (tau_kernel): one wave per row. Pass 1: wave max m (butterfly).
//   Since sum(max(x-tau,0))=1 and max alone contributes <=1, tau in
//   [m-1, m) => support subset of {x > m-1} (~21 elems/row, Gaussian).
//   Pass 2 (L2/LLC-warm): capture candidates into a 7-deep per-lane
//   register queue; Michelot via shuffles; lane0 writes tau[row] to d_ws.
//   Overflow (ballot) -> rescan fallback. (Math verified in R4: 4.9e-4.)
//
// K2 (apply_kernel): pure copy-shaped stream: out = max(x - tau[row], 0),
//   4 independent float4 per thread, nontemporal stores. This is the A/B
//   probe for achievable BW: no phases, no reductions, no barriers.

#define D 8192
#define ROWS 8192
#define NF4 (D / 4 / 64)  // 32 float4 per lane per row
#define CAPL 7
#define NEG_HUGE -3.402823466e+38f

typedef float v4f __attribute__((ext_vector_type(4)));

__global__ __launch_bounds__(256) void tau_kernel(
    const float* __restrict__ x, float* __restrict__ tau_out) {
  const int lane = threadIdx.x & 63;
  const int wave = threadIdx.x >> 6;
  const long long row = (long long)blockIdx.x * 4 + wave;
  const float4* __restrict__ xr = (const float4*)(x + row * (long long)D);

  // ---- pass 1: exact row max ----
  float m = NEG_HUGE;
#pragma unroll 8
  for (int j = 0; j < NF4; ++j) {
    float4 f = xr[lane + 64 * j];
    m = fmaxf(m, fmaxf(fmaxf(f.x, f.y), fmaxf(f.z, f.w)));
  }
#pragma unroll
  for (int o = 1; o < 64; o <<= 1) m = fmaxf(m, __shfl_xor(m, o, 64));
  const float L = m - 1.0f;  // tau >= L always

  // ---- pass 2 (cache-warm): capture candidates > L into register queue ----
  float tv[CAPL];
  int cnt = 0;
#pragma unroll
  for (int k = 0; k < CAPL; ++k) tv[k] = NEG_HUGE;

#define PUSHV(val)                                                  \
  do {                                                              \
    tv[6] = tv[5]; tv[5] = tv[4]; tv[4] = tv[3]; tv[3] = tv[2];     \
    tv[2] = tv[1]; tv[1] = tv[0]; tv[0] = (val); ++cnt;             \
  } while (0)

#pragma unroll 4
  for (int j = 0; j < NF4; ++j) {
    float4 f = xr[lane + 64 * j];
    if (f.x > L) PUSHV(f.x);
    if (f.y > L) PUSHV(f.y);
    if (f.z > L) PUSHV(f.z);
    if (f.w > L) PUSHV(f.w);
  }

  const unsigned long long ovf = __ballot(cnt > CAPL);
  float tau;

  if (ovf == 0ULL) {
    // Michelot on register-resident candidates (shuffles only).
    float s = 0.f, c = (float)cnt;
#pragma unroll
    for (int k = 0; k < CAPL; ++k) s += (k < cnt) ? tv[k] : 0.f;
#pragma unroll
    for (int o = 1; o < 64; o <<= 1) {
      s += __shfl_xor(s, o, 64);
      c += __shfl_xor(c, o, 64);
    }
    tau = (s - 1.0f) / c;  // c >= 1: the max is always a candidate
    float prev = c;
    for (int it = 0; it < 512; ++it) {
      float s2 = 0.f, c2 = 0.f;
#pragma unroll
      for (int k = 0; k < CAPL; ++k)
        if (tv[k] > tau) { s2 += tv[k]; c2 += 1.f; }
#pragma unroll
      for (int o = 1; o < 64; o <<= 1) {
        s2 += __shfl_xor(s2, o, 64);
        c2 += __shfl_xor(c2, o, 64);
      }
      if (c2 == prev) break;  // support stable => tau exact
      tau = (s2 - 1.0f) / c2;
      prev = c2;
    }
  } else {
    // Rare fallback (e.g. near-constant rows): rescan Michelot from cache.
    tau = L;
    float prev = -1.f;
    for (int it = 0; it < 256; ++it) {
      float s = 0.f, c = 0.f;
#pragma unroll 4
      for (int j = 0; j < NF4; ++j) {
        float4 f = xr[lane + 64 * j];
        if (f.x > tau) { s += f.x; c += 1.f; }
        if (f.y > tau) { s += f.y; c += 1.f; }
        if (f.z > tau) { s += f.z; c += 1.f; }
        if (f.w > tau) { s += f.w; c += 1.f; }
      }
#pragma unroll
      for (int o = 1; o < 64; o <<= 1) {
        s += __shfl_xor(s, o, 64);
        c += __shfl_xor(c, o, 64);
      }
      if (c == prev) break;
      tau = (s - 1.0f) / c;
      prev = c;
    }
  }

  if (lane == 0) tau_out[row] = tau;
}

// K2: pure streaming apply. 4 independent float4 per thread (loads all
// issued before any use), nontemporal stores.
__global__ __launch_bounds__(256) void apply_kernel(
    const float* __restrict__ x, const float* __restrict__ tau,
    float* __restrict__ out) {
  const int S = gridDim.x * 256;  // threads total = n4/4
  const int gid = blockIdx.x * 256 + threadIdx.x;
  const float4* __restrict__ x4 = (const float4*)x;
  float4* __restrict__ o4 = (float4*)out;

  const int i0 = gid, i1 = gid + S, i2 = gid + 2 * S, i3 = gid + 3 * S;
  float4 a0 = x4[i0];
  float4 a1 = x4[i1];
  float4 a2 = x4[i2];
  float4 a3 = x4[i3];
  float t0 = tau[i0 >> 11];  // 2048 float4 per row
  float t1 = tau[i1 >> 11];
  float t2 = tau[i2 >> 11];
  float t3 = tau[i3 >> 11];

  v4f r0 = {fmaxf(a0.x - t0, 0.f), fmaxf(a0.y - t0, 0.f),
            fmaxf(a0.z - t0, 0.f), fmaxf(a0.w - t0, 0.f)};
  v4f r1 = {fmaxf(a1.x - t1, 0.f), fmaxf(a1.y - t1, 0.f),
            fmaxf(a1.z - t1, 0.f), fmaxf(a1.w - t1, 0.f)};
  v4f r2 = {fmaxf(a2.x - t2, 0.f), fmaxf(a2.y - t2, 0.f),
            fmaxf(a2.z - t2, 0.f), fmaxf(a2.w - t2, 0.f)};
  v4f r3 = {fmaxf(a3.x - t3, 0.f), fmaxf(a3.y - t3, 0.f),
            fmaxf(a3.z - t3, 0.f), fmaxf(a3.w - t3, 0.f)};
  __builtin_nontemporal_store(r0, (v4f*)&o4[i0]);
  __builtin_nontemporal_store(r1, (v4f*)&o4[i1]);
  __builtin_nontemporal_store(r2, (v4f*)&o4[i2]);
  __builtin_nontemporal_store(r3, (v4f*)&o4[i3]);
}

extern "C" void kernel_launch(void* const* d_in, const int* in_sizes, int n_in,
                              void* d_out, int out_size, void* d_ws, size_t ws_size,
                              hipStream_t stream) {
  const float* x = (const float*)d_in[0];
  float* out = (float*)d_out;
  float* tau = (float*)d_ws;  // ROWS floats of scratch

  tau_kernel<<<ROWS / 4, 256, 0, stream>>>(x, tau);

  const int n4 = ROWS * (D / 4);            // 16,777,216 float4
  const int blocks = n4 / 4 / 256;          // 16384 blocks, 4 float4/thread
  apply_kernel<<<blocks, 256, 0, stream>>>(x, tau, out);
}